// Round 7
// baseline (35.946 us; speedup 1.0000x reference)
//
#include <hip/hip_runtime.h>

typedef float f2 __attribute__((ext_vector_type(2)));   // complex (re, im)

constexpr int NQ   = 10;
constexpr int CDIM = 768;
constexpr int NL   = 3;
constexpr int NR   = 8;     // index bits 6..8 in the register index; bit 9 = wave parity
constexpr int WAVES = 4;    // waves per block = 2 samples * 2 waves

// ---------- cross-lane primitives (all VALU, no LDS pipe) ----------

template<int CTRL>
__device__ __forceinline__ float dppmov(float x) {
    return __int_as_float(__builtin_amdgcn_update_dpp(
        __float_as_int(x), __float_as_int(x), CTRL, 0xF, 0xF, true));
}

// y[l] = x[l ^ MASK] for MASK in {1,2,4,8}
template<int MASK>
__device__ __forceinline__ float lxor(float x, int lane) {
    static_assert(MASK == 1 || MASK == 2 || MASK == 4 || MASK == 8, "");
    if constexpr (MASK == 1)      return dppmov<0xB1>(x);   // quad_perm [1,0,3,2]
    else if constexpr (MASK == 2) return dppmov<0x4E>(x);   // quad_perm [2,3,0,1]
    else if constexpr (MASK == 4) {
        const float a = dppmov<0x104>(x);   // row_shl:4 -> src[i+4] (bit2=0 lanes)
        const float b = dppmov<0x114>(x);   // row_shr:4 -> src[i-4] (bit2=1 lanes)
        return ((lane >> 2) & 1) ? b : a;
    }
    else                          return dppmov<0x128>(x);  // row_ror:8 == xor8
}

// B in {4,5}: lo = x[l & ~(1<<B)], hi = x[l | (1<<B)]  (one swap instr)
template<int B>
__device__ __forceinline__ void swap2(float x, float& lo, float& hi) {
    const unsigned xu = __float_as_uint(x);
#if __has_builtin(__builtin_amdgcn_permlane16_swap) && __has_builtin(__builtin_amdgcn_permlane32_swap)
    if constexpr (B == 4) {
        auto r = __builtin_amdgcn_permlane16_swap(xu, xu, false, false);
        lo = __uint_as_float(r[0]); hi = __uint_as_float(r[1]);
    } else {
        auto r = __builtin_amdgcn_permlane32_swap(xu, xu, false, false);
        lo = __uint_as_float(r[0]); hi = __uint_as_float(r[1]);
    }
#else
    float d, s;
    if constexpr (B == 4)
        asm("v_mov_b32 %0, %2\n\tv_mov_b32 %1, %2\n\ts_nop 1\n\t"
            "v_permlane16_swap_b32 %0, %1"
            : "=&v"(d), "=&v"(s) : "v"(x));
    else
        asm("v_mov_b32 %0, %2\n\tv_mov_b32 %1, %2\n\ts_nop 1\n\t"
            "v_permlane32_swap_b32 %0, %1"
            : "=&v"(d), "=&v"(s) : "v"(x));
    lo = d; hi = s;
#endif
}

__device__ __forceinline__ float wave_sum(float v) {
    v += dppmov<0xB1>(v);    // xor1
    v += dppmov<0x4E>(v);    // xor2
    v += dppmov<0x141>(v);   // row_half_mirror = xor7 (bits 0-1 uniform)
    v += dppmov<0x140>(v);   // row_mirror = xor15 (bits 0-2 uniform)
    float lo, hi;
    swap2<4>(v, lo, hi); v = lo + hi;
    swap2<5>(v, lo, hi); v = lo + hi;
    return v;
}

// ---------- complex helpers (packed-math friendly) ----------

__device__ __forceinline__ f2 swapneg(f2 b) { f2 r; r.x = -b.y; r.y = b.x; return r; }
__device__ __forceinline__ f2 cmul(f2 a, f2 b) { return b * a.x + swapneg(b) * a.y; }
__device__ __forceinline__ f2 cfma(f2 a, f2 b, f2 acc) { return acc + b * a.x + swapneg(b) * a.y; }

// ---------- 1-qubit gate on LOCAL index-bit B (0..8) ----------

template<int B>
__device__ __forceinline__ void gate_bit(f2 (&v)[NR], int lane,
                                         f2 g00, f2 g01, f2 g10, f2 g11) {
    static_assert(B <= 8, "wave bit handled separately");
    if constexpr (B >= 6) {                       // register bit: pure in-reg
        constexpr int rb = B - 6;
#pragma unroll
        for (int p = 0; p < NR / 2; ++p) {
            const int r0 = ((p >> rb) << (rb + 1)) | (p & ((1 << rb) - 1));
            const int r1 = r0 | (1 << rb);
            const f2 a0 = v[r0], a1 = v[r1];
            v[r0] = cfma(g01, a1, cmul(g00, a0));
            v[r1] = cfma(g11, a1, cmul(g10, a0));
        }
    } else if constexpr (B >= 4) {                // lane bit via permlane swap
        const bool hb = (lane >> B) & 1;
        const f2 A  = hb ? g10 : g00;             // coeff on lo value
        const f2 Bc = hb ? g11 : g01;             // coeff on hi value
#pragma unroll
        for (int r = 0; r < NR; ++r) {
            float lx, hx, ly, hy;
            swap2<B>(v[r].x, lx, hx);
            swap2<B>(v[r].y, ly, hy);
            f2 lo; lo.x = lx; lo.y = ly;
            f2 hi; hi.x = hx; hi.y = hy;
            v[r] = cfma(Bc, hi, cmul(A, lo));
        }
    } else {                                      // lane bit via DPP
        const bool hb = (lane >> B) & 1;
        const f2 cO = hb ? g11 : g00;
        const f2 cP = hb ? g10 : g01;
#pragma unroll
        for (int r = 0; r < NR; ++r) {
            f2 p;
            p.x = lxor<(1 << B)>(v[r].x, lane);
            p.y = lxor<(1 << B)>(v[r].y, lane);
            v[r] = cfma(cP, p, cmul(cO, v[r]));
        }
    }
}

// partner value x[l ^ (1<<BT)] for lane-resident target bit
template<int BT>
__device__ __forceinline__ float partner(float x, int lane) {
    if constexpr (BT >= 4) {
        float lo, hi; swap2<BT>(x, lo, hi);
        return ((lane >> BT) & 1) ? lo : hi;
    } else return lxor<(1 << BT)>(x, lane);
}

// ---------- CNOT (bits: 9 = wave, 6..8 = reg, 0..5 = lane) ----------

template<int BC, int BT>
__device__ __forceinline__ void cnot(f2 (&v)[NR], int lane, int hs,
                                     f2* mybuf, const f2* pbuf) {
    if constexpr (BC == 9) {                      // wave control: h=1 local swap
        if (hs) {
            if constexpr (BT >= 6) {
                constexpr int rt = BT - 6;
#pragma unroll
                for (int p = 0; p < NR / 2; ++p) {
                    const int r0 = ((p >> rt) << (rt + 1)) | (p & ((1 << rt) - 1));
                    const int r1 = r0 | (1 << rt);
                    const f2 t = v[r0]; v[r0] = v[r1]; v[r1] = t;
                }
            } else {
#pragma unroll
                for (int r = 0; r < NR; ++r) {
                    f2 n;
                    n.x = partner<BT>(v[r].x, lane);
                    n.y = partner<BT>(v[r].y, lane);
                    v[r] = n;
                }
            }
        }
    } else if constexpr (BT == 9) {               // wave target, lane control
        static_assert(BC < 6, "");
#pragma unroll
        for (int r = 0; r < NR; ++r) mybuf[r * 64 + lane] = v[r];
        __syncthreads();
        const bool c = (lane >> BC) & 1;
#pragma unroll
        for (int r = 0; r < NR; ++r) {
            const f2 pv = pbuf[r * 64 + lane];
            v[r] = c ? pv : v[r];
        }
        __syncthreads();
    } else if constexpr (BC >= 6 && BT >= 6) {    // both reg: free rename
        constexpr int rc = BC - 6, rt = BT - 6;
#pragma unroll
        for (int r = 0; r < NR; ++r)
            if (((r >> rc) & 1) && !((r >> rt) & 1)) {
                const int r1 = r | (1 << rt);
                const f2 t = v[r]; v[r] = v[r1]; v[r1] = t;
            }
    } else if constexpr (BC >= 6) {               // reg control, lane target
        constexpr int rc = BC - 6;
#pragma unroll
        for (int r = 0; r < NR; ++r)
            if ((r >> rc) & 1) {
                f2 n;
                n.x = partner<BT>(v[r].x, lane);
                n.y = partner<BT>(v[r].y, lane);
                v[r] = n;
            }
    } else if constexpr (BT >= 6) {               // lane control, reg target
        constexpr int rt = BT - 6;
        const bool c = (lane >> BC) & 1;
#pragma unroll
        for (int p = 0; p < NR / 2; ++p) {
            const int r0 = ((p >> rt) << (rt + 1)) | (p & ((1 << rt) - 1));
            const int r1 = r0 | (1 << rt);
            const f2 a = v[r0], b = v[r1];
            v[r0] = c ? b : a;
            v[r1] = c ? a : b;
        }
    } else {                                      // both lane
        const bool c = (lane >> BC) & 1;
#pragma unroll
        for (int r = 0; r < NR; ++r) {
            f2 n;
            n.x = c ? partner<BT>(v[r].x, lane) : v[r].x;
            n.y = c ? partner<BT>(v[r].y, lane) : v[r].y;
            v[r] = n;
        }
    }
}

// ---------- layer drivers ----------

// Rot gate on wire 0 (= wave bit): cross-wave exchange
template<int L>
__device__ __forceinline__ void rot_wave_gate(f2 (&v)[NR], int lane, int hs,
                                              f2* mybuf, const f2* pbuf,
                                              const float* __restrict__ gates) {
    const float4* g4 = (const float4*)gates;
    const float4 p0 = g4[(L * NQ) * 2];
    const float4 p1 = g4[(L * NQ) * 2 + 1];
    f2 g00 = {p0.x, p0.y}, g01 = {p0.z, p0.w};
    f2 g10 = {p1.x, p1.y}, g11 = {p1.z, p1.w};
    const f2 cO = hs ? g11 : g00;   // coeff on own half
    const f2 cP = hs ? g10 : g01;   // coeff on partner half
#pragma unroll
    for (int r = 0; r < NR; ++r) mybuf[r * 64 + lane] = v[r];
    __syncthreads();
#pragma unroll
    for (int r = 0; r < NR; ++r) {
        const f2 pv = pbuf[r * 64 + lane];
        v[r] = cfma(cP, pv, cmul(cO, v[r]));
    }
    __syncthreads();
}

template<int L, int Q = 1>
__device__ __forceinline__ void rot_layer_rest(f2 (&v)[NR], int lane,
                                               const float* __restrict__ gates) {
    if constexpr (Q < NQ) {
        const float4* g4 = (const float4*)gates;       // uniform -> s_load
        const float4 p0 = g4[(L * NQ + Q) * 2];
        const float4 p1 = g4[(L * NQ + Q) * 2 + 1];
        f2 g00 = {p0.x, p0.y}, g01 = {p0.z, p0.w};
        f2 g10 = {p1.x, p1.y}, g11 = {p1.z, p1.w};
        gate_bit<9 - Q>(v, lane, g00, g01, g10, g11);
        rot_layer_rest<L, Q + 1>(v, lane, gates);
    }
}

template<int L, int I = 0>
__device__ __forceinline__ void cnot_ring(f2 (&v)[NR], int lane, int hs,
                                          f2* mybuf, const f2* pbuf) {
    if constexpr (I < NQ) {
        constexpr int R = (L % (NQ - 1)) + 1;
        cnot<9 - I, 9 - ((I + R) % NQ)>(v, lane, hs, mybuf, pbuf);
        cnot_ring<L, I + 1>(v, lane, hs, mybuf, pbuf);
    }
}

// precompute the 30 wave-uniform Rot matrices once
__global__ void prep_gates(const float* __restrict__ wts, float* __restrict__ gates) {
    const int t = threadIdx.x;
    if (t < NL * NQ) {
        const float phi = wts[t * 3 + 0];
        const float th  = wts[t * 3 + 1];
        const float om  = wts[t * 3 + 2];
        float st, ct, sA, cA, sB, cB;
        sincosf(0.5f * th, &st, &ct);
        sincosf(0.5f * (phi + om), &sA, &cA);
        sincosf(0.5f * (phi - om), &sB, &cB);
        float* g = gates + t * 8;
        g[0] =  ct * cA; g[1] = -ct * sA;   // g00
        g[2] = -st * cB; g[3] = -st * sB;   // g01
        g[4] =  st * cB; g[5] = -st * sB;   // g10
        g[6] =  ct * cA; g[7] =  ct * sA;   // g11
    }
}

// ---------- main kernel: 2 waves per sample, 4 waves/SIMD ----------

__global__ __launch_bounds__(64 * WAVES, 4) void qembed(
    const float* __restrict__ z,     // (B, CDIM)
    const float* __restrict__ Win,   // (CDIM, NQ)
    const float* __restrict__ bin,   // (NQ)
    const float* __restrict__ gates, // (NL*NQ, 8) precomputed
    const float* __restrict__ Wout,  // (NQ, CDIM)
    const float* __restrict__ bout,  // (CDIM)
    float* __restrict__ out)         // (B, CDIM)
{
    __shared__ f2 xch[WAVES][NR * 64];      // 16 KB
    __shared__ float sbuf[WAVES][16];       // angle / ev partials

    const int wave = threadIdx.x >> 6;
    const int lane = threadIdx.x & 63;
    const int hs   = __builtin_amdgcn_readfirstlane(wave & 1);  // index bit 9 (wire 0)
    const int samp = blockIdx.x * (WAVES / 2) + (wave >> 1);
    f2* mybuf       = xch[wave];
    const f2* pbuf  = xch[wave ^ 1];

    // ---- angles = z[samp] @ Win + bin (k-range split across wave pair) ----
    float ang[NQ];
    {
        float acc[NQ];
#pragma unroll
        for (int q = 0; q < NQ; ++q) acc[q] = 0.f;
        const float* zrow = z + (size_t)samp * CDIM + hs * (CDIM / 2);
#pragma unroll
        for (int j = 0; j < CDIM / 128; ++j) {
            const int k = lane + j * 64;
            const float zv = zrow[k];
            const f2* wr = (const f2*)(Win + (hs * (CDIM / 2) + k) * NQ);
#pragma unroll
            for (int h = 0; h < NQ / 2; ++h) {
                const f2 w = wr[h];
                acc[2 * h]     += zv * w.x;
                acc[2 * h + 1] += zv * w.y;
            }
        }
#pragma unroll
        for (int q = 0; q < NQ; ++q) ang[q] = wave_sum(acc[q]);
        if (lane == 0) {
#pragma unroll
            for (int q = 0; q < NQ; ++q) sbuf[wave][q] = ang[q];
        }
        __syncthreads();
#pragma unroll
        for (int q = 0; q < NQ; ++q) ang[q] += sbuf[wave ^ 1][q] + bin[q];
        __syncthreads();
    }

    // ---- layer 0 on |0..0>: product state built directly ----
    // fused F_q = Rot(l0,q) * RX(ang_q); only its first column (f0,f1) matters
    f2 f0[NQ], f1[NQ];
    {
        const float4* g4 = (const float4*)gates;       // uniform -> s_load
#pragma unroll
        for (int q = 0; q < NQ; ++q) {
            const float4 p0 = g4[q * 2];
            const float4 p1 = g4[q * 2 + 1];
            float s, c;
            __sincosf(0.5f * ang[q], &s, &c);
            f2 a, b;
            a.x = p0.x * c + s * p0.w;  a.y = p0.y * c - s * p0.z;
            b.x = p1.x * c + s * p1.w;  b.y = p1.y * c - s * p1.z;
            f0[q] = a; f1[q] = b;
        }
    }
    // lane bits b 0..5 <-> wires 9..4
    f2 s0 = ((lane >> 0) & 1) ? f1[9] : f0[9];
    f2 s1 = ((lane >> 1) & 1) ? f1[8] : f0[8];
    f2 s2 = ((lane >> 2) & 1) ? f1[7] : f0[7];
    f2 s3 = ((lane >> 3) & 1) ? f1[6] : f0[6];
    f2 s4 = ((lane >> 4) & 1) ? f1[5] : f0[5];
    f2 s5 = ((lane >> 5) & 1) ? f1[4] : f0[4];
    f2 L = cmul(cmul(cmul(s0, s1), cmul(s2, s3)), cmul(s4, s5));
    L = cmul(L, hs ? f1[0] : f0[0]);               // wave bit 9 <-> wire 0

    // reg bits 0,1,2 <-> index bits 6,7,8 <-> wires 3,2,1
    const f2 W0 = cmul(L, f0[1]);
    const f2 W1 = cmul(L, f1[1]);
    f2 T2[4];
#pragma unroll
    for (int j = 0; j < 4; ++j)
        T2[j] = cmul((j & 1) ? f1[3] : f0[3], (j & 2) ? f1[2] : f0[2]);
    f2 v[NR];
#pragma unroll
    for (int r = 0; r < NR; ++r) v[r] = cmul((r & 4) ? W1 : W0, T2[r & 3]);

    // ---- remaining circuit ----
    cnot_ring<0>(v, lane, hs, mybuf, pbuf);
    rot_wave_gate<1>(v, lane, hs, mybuf, pbuf, gates);
    rot_layer_rest<1>(v, lane, gates);
    cnot_ring<1>(v, lane, hs, mybuf, pbuf);
    rot_wave_gate<2>(v, lane, hs, mybuf, pbuf, gates);
    rot_layer_rest<2>(v, lane, gates);
    cnot_ring<2>(v, lane, hs, mybuf, pbuf);

    // ---- expectation values (partials over own half) ----
    float pr[NR];
#pragma unroll
    for (int r = 0; r < NR; ++r) pr[r] = v[r].x * v[r].x + v[r].y * v[r].y;

    float sumAll = 0.f;
#pragma unroll
    for (int r = 0; r < NR; ++r) sumAll += pr[r];

    float sgn[3];
#pragma unroll
    for (int rb = 0; rb < 3; ++rb) {
        float s = 0.f;
#pragma unroll
        for (int r = 0; r < NR; ++r) s += ((r >> rb) & 1) ? -pr[r] : pr[r];
        sgn[rb] = s;
    }

    float ev[NQ];
#pragma unroll
    for (int w = 0; w < NQ; ++w) {
        const int b = 9 - w;
        float val;
        if (b == 9)       val = sumAll;            // wire 0: sign applied at combine
        else if (b >= 6)  val = sgn[b - 6];
        else              val = ((lane >> b) & 1) ? -sumAll : sumAll;
        ev[w] = wave_sum(val);
    }

    if (lane == 0) {
#pragma unroll
        for (int w = 0; w < NQ; ++w) sbuf[wave][w] = ev[w];
    }
    __syncthreads();
    {
        const float p0 = sbuf[wave ^ 1][0];
        ev[0] = hs ? (p0 - ev[0]) : (ev[0] - p0);
#pragma unroll
        for (int w = 1; w < NQ; ++w) ev[w] += sbuf[wave ^ 1][w];
    }

    // ---- out[samp] = ev @ Wout + bout (row split across wave pair) ----
#pragma unroll
    for (int j = 0; j < CDIM / 128; ++j) {
        const int d = hs * (CDIM / 2) + lane + j * 64;
        float o = bout[d];
#pragma unroll
        for (int q = 0; q < NQ; ++q) o += ev[q] * Wout[q * CDIM + d];
        out[(size_t)samp * CDIM + d] = o;
    }
}

extern "C" void kernel_launch(void* const* d_in, const int* in_sizes, int n_in,
                              void* d_out, int out_size, void* d_ws, size_t ws_size,
                              hipStream_t stream) {
    const float* z    = (const float*)d_in[0];
    const float* Win  = (const float*)d_in[1];
    const float* bin  = (const float*)d_in[2];
    const float* wts  = (const float*)d_in[3];
    const float* Wout = (const float*)d_in[4];
    const float* bout = (const float*)d_in[5];
    float* outp       = (float*)d_out;
    float* gates      = (float*)d_ws;       // 30 gates * 8 floats = 960 B

    prep_gates<<<1, 64, 0, stream>>>(wts, gates);

    const int batch  = in_sizes[0] / CDIM;         // 2048
    const int blocks = batch / (WAVES / 2);        // 1024 (2 samples/block)
    qembed<<<blocks, 64 * WAVES, 0, stream>>>(z, Win, bin, gates, Wout, bout, outp);
}

// Round 8
// 34.673 us; speedup vs baseline: 1.0367x; 1.0367x over previous
//
#include <hip/hip_runtime.h>

typedef float f2 __attribute__((ext_vector_type(2)));   // complex (re, im)

constexpr int NQ   = 10;
constexpr int CDIM = 768;
constexpr int NL   = 3;
constexpr int NREG = 16;   // index bits 6..9 in the register index
constexpr int WPB  = 4;    // waves (= samples) per block

// ---------- cross-lane primitives (all VALU, no LDS pipe) ----------

template<int CTRL>
__device__ __forceinline__ float dppmov(float x) {
    return __int_as_float(__builtin_amdgcn_update_dpp(
        __float_as_int(x), __float_as_int(x), CTRL, 0xF, 0xF, true));
}

// y[l] = x[l ^ MASK] for MASK in {1,2,4,8}
template<int MASK>
__device__ __forceinline__ float lxor(float x, int lane) {
    static_assert(MASK == 1 || MASK == 2 || MASK == 4 || MASK == 8, "");
    if constexpr (MASK == 1)      return dppmov<0xB1>(x);   // quad_perm [1,0,3,2]
    else if constexpr (MASK == 2) return dppmov<0x4E>(x);   // quad_perm [2,3,0,1]
    else if constexpr (MASK == 4) {
        const float a = dppmov<0x104>(x);   // row_shl:4 -> src[i+4] (bit2=0 lanes)
        const float b = dppmov<0x114>(x);   // row_shr:4 -> src[i-4] (bit2=1 lanes)
        return ((lane >> 2) & 1) ? b : a;
    }
    else                          return dppmov<0x128>(x);  // row_ror:8 == xor8
}

// B in {4,5}: lo = x[l & ~(1<<B)], hi = x[l | (1<<B)]  (one swap instr)
template<int B>
__device__ __forceinline__ void swap2(float x, float& lo, float& hi) {
    const unsigned xu = __float_as_uint(x);
#if __has_builtin(__builtin_amdgcn_permlane16_swap) && __has_builtin(__builtin_amdgcn_permlane32_swap)
    if constexpr (B == 4) {
        auto r = __builtin_amdgcn_permlane16_swap(xu, xu, false, false);
        lo = __uint_as_float(r[0]); hi = __uint_as_float(r[1]);
    } else {
        auto r = __builtin_amdgcn_permlane32_swap(xu, xu, false, false);
        lo = __uint_as_float(r[0]); hi = __uint_as_float(r[1]);
    }
#else
    float d, s;
    if constexpr (B == 4)
        asm("v_mov_b32 %0, %2\n\tv_mov_b32 %1, %2\n\ts_nop 1\n\t"
            "v_permlane16_swap_b32 %0, %1"
            : "=&v"(d), "=&v"(s) : "v"(x));
    else
        asm("v_mov_b32 %0, %2\n\tv_mov_b32 %1, %2\n\ts_nop 1\n\t"
            "v_permlane32_swap_b32 %0, %1"
            : "=&v"(d), "=&v"(s) : "v"(x));
    lo = d; hi = s;
#endif
}

__device__ __forceinline__ float wave_sum(float v) {
    v += dppmov<0xB1>(v);    // xor1
    v += dppmov<0x4E>(v);    // xor2
    v += dppmov<0x141>(v);   // row_half_mirror = xor7 (bits 0-1 uniform)
    v += dppmov<0x140>(v);   // row_mirror = xor15 (bits 0-2 uniform)
    float lo, hi;
    swap2<4>(v, lo, hi); v = lo + hi;
    swap2<5>(v, lo, hi); v = lo + hi;
    return v;
}

// ---------- complex helpers (packed-math friendly) ----------

__device__ __forceinline__ f2 swapneg(f2 b) { f2 r; r.x = -b.y; r.y = b.x; return r; }
__device__ __forceinline__ f2 cmul(f2 a, f2 b) { return b * a.x + swapneg(b) * a.y; }
__device__ __forceinline__ f2 cfma(f2 a, f2 b, f2 acc) { return acc + b * a.x + swapneg(b) * a.y; }

// ---------- 1-qubit gate on index-bit B (wire w -> B = 9 - w) ----------

template<int B>
__device__ __forceinline__ void gate_bit(f2 (&v)[NREG], int lane,
                                         f2 g00, f2 g01, f2 g10, f2 g11) {
    if constexpr (B >= 6) {                       // register bit: pure in-reg
        constexpr int rb = B - 6;
#pragma unroll
        for (int p = 0; p < NREG / 2; ++p) {
            const int r0 = ((p >> rb) << (rb + 1)) | (p & ((1 << rb) - 1));
            const int r1 = r0 | (1 << rb);
            const f2 a0 = v[r0], a1 = v[r1];
            v[r0] = cfma(g01, a1, cmul(g00, a0));
            v[r1] = cfma(g11, a1, cmul(g10, a0));
        }
    } else if constexpr (B >= 4) {                // lane bit via permlane swap
        const bool hb = (lane >> B) & 1;
        const f2 A  = hb ? g10 : g00;             // coeff on lo value
        const f2 Bc = hb ? g11 : g01;             // coeff on hi value
#pragma unroll
        for (int r = 0; r < NREG; ++r) {
            float lx, hx, ly, hy;
            swap2<B>(v[r].x, lx, hx);
            swap2<B>(v[r].y, ly, hy);
            f2 lo; lo.x = lx; lo.y = ly;
            f2 hi; hi.x = hx; hi.y = hy;
            v[r] = cfma(Bc, hi, cmul(A, lo));
        }
    } else {                                      // lane bit via DPP
        const bool hb = (lane >> B) & 1;
        const f2 cO = hb ? g11 : g00;
        const f2 cP = hb ? g10 : g01;
#pragma unroll
        for (int r = 0; r < NREG; ++r) {
            f2 p;
            p.x = lxor<(1 << B)>(v[r].x, lane);
            p.y = lxor<(1 << B)>(v[r].y, lane);
            v[r] = cfma(cP, p, cmul(cO, v[r]));
        }
    }
}

// partner value x[l ^ (1<<BT)] for lane-resident target bit
template<int BT>
__device__ __forceinline__ float partner(float x, int lane) {
    if constexpr (BT >= 4) {
        float lo, hi; swap2<BT>(x, lo, hi);
        return ((lane >> BT) & 1) ? lo : hi;
    } else return lxor<(1 << BT)>(x, lane);
}

// ---------- CNOT ----------

template<int BC, int BT>
__device__ __forceinline__ void cnot(f2 (&v)[NREG], int lane) {
    if constexpr (BC >= 6 && BT >= 6) {           // both reg: free rename
        constexpr int rc = BC - 6, rt = BT - 6;
#pragma unroll
        for (int r = 0; r < NREG; ++r)
            if (((r >> rc) & 1) && !((r >> rt) & 1)) {
                const int r1 = r | (1 << rt);
                const f2 t = v[r]; v[r] = v[r1]; v[r1] = t;
            }
    } else if constexpr (BC >= 6) {               // reg control, lane target
        constexpr int rc = BC - 6;
#pragma unroll
        for (int r = 0; r < NREG; ++r)
            if ((r >> rc) & 1) {
                f2 n;
                n.x = partner<BT>(v[r].x, lane);
                n.y = partner<BT>(v[r].y, lane);
                v[r] = n;
            }
    } else if constexpr (BT >= 6) {               // lane control, reg target
        constexpr int rt = BT - 6;
        const bool c = (lane >> BC) & 1;
#pragma unroll
        for (int p = 0; p < NREG / 2; ++p) {
            const int r0 = ((p >> rt) << (rt + 1)) | (p & ((1 << rt) - 1));
            const int r1 = r0 | (1 << rt);
            const f2 a = v[r0], b = v[r1];
            v[r0] = c ? b : a;
            v[r1] = c ? a : b;
        }
    } else {                                      // both lane
        const bool c = (lane >> BC) & 1;
#pragma unroll
        for (int r = 0; r < NREG; ++r) {
            f2 n;
            n.x = c ? partner<BT>(v[r].x, lane) : v[r].x;
            n.y = c ? partner<BT>(v[r].y, lane) : v[r].y;
            v[r] = n;
        }
    }
}

// ---------- layer drivers ----------

template<int L, int Q = 0>
__device__ __forceinline__ void rot_layer(f2 (&v)[NREG], int lane,
                                          const float* __restrict__ gates) {
    if constexpr (Q < NQ) {
        const float4* g4 = (const float4*)gates;       // uniform -> s_load
        const float4 p0 = g4[(L * NQ + Q) * 2];
        const float4 p1 = g4[(L * NQ + Q) * 2 + 1];
        f2 g00 = {p0.x, p0.y}, g01 = {p0.z, p0.w};
        f2 g10 = {p1.x, p1.y}, g11 = {p1.z, p1.w};
        gate_bit<9 - Q>(v, lane, g00, g01, g10, g11);
        rot_layer<L, Q + 1>(v, lane, gates);
    }
}

template<int L, int I = 0>
__device__ __forceinline__ void cnot_ring(f2 (&v)[NREG], int lane) {
    if constexpr (I < NQ) {
        constexpr int R = (L % (NQ - 1)) + 1;
        cnot<9 - I, 9 - ((I + R) % NQ)>(v, lane);
        cnot_ring<L, I + 1>(v, lane);
    }
}

// ---------- ring-2 absorbed measurement ----------
// Final CNOT ring (r=3) is a classical permutation; measuring Z_w after it
// equals measuring parity(x & M_w) before it, with M_t ^= M_c accumulated in
// gate order (current values). Computed at compile time.
constexpr unsigned ring2_mask(int w) {
    unsigned M[NQ] = {};
    for (int i = 0; i < NQ; ++i) M[i] = 1u << (9 - i);
    for (int i = 0; i < NQ; ++i) M[(i + 3) % NQ] ^= M[i];
    return M[w];
}

template<unsigned MR>
__device__ __forceinline__ float regsum16(const float (&pr)[NREG]) {
    float s = 0.f;
#pragma unroll
    for (int r = 0; r < NREG; ++r)
        s = (__builtin_popcount((unsigned)r & MR) & 1) ? s - pr[r] : s + pr[r];
    return s;
}

template<int W = 0>
__device__ __forceinline__ void measure_all(const float (&pr)[NREG], int lane,
                                            float (&ev)[NQ]) {
    if constexpr (W < NQ) {
        constexpr unsigned m  = ring2_mask(W);
        constexpr unsigned mr = (m >> 6) & 0xFu;   // register-bit part
        constexpr unsigned ml = m & 63u;           // lane-bit part
        float s = regsum16<mr>(pr);
        if constexpr (ml != 0) {
            const unsigned flip = (unsigned)((__popc(lane & (int)ml) & 1)) << 31;
            s = __uint_as_float(__float_as_uint(s) ^ flip);
        }
        ev[W] = wave_sum(s);
        measure_all<W + 1>(pr, lane, ev);
    }
}

// precompute the 30 wave-uniform Rot matrices once
__global__ void prep_gates(const float* __restrict__ wts, float* __restrict__ gates) {
    const int t = threadIdx.x;
    if (t < NL * NQ) {
        const float phi = wts[t * 3 + 0];
        const float th  = wts[t * 3 + 1];
        const float om  = wts[t * 3 + 2];
        float st, ct, sA, cA, sB, cB;
        sincosf(0.5f * th, &st, &ct);
        sincosf(0.5f * (phi + om), &sA, &cA);
        sincosf(0.5f * (phi - om), &sB, &cB);
        float* g = gates + t * 8;
        g[0] =  ct * cA; g[1] = -ct * sA;   // g00
        g[2] = -st * cB; g[3] = -st * sB;   // g01
        g[4] =  st * cB; g[5] = -st * sB;   // g10
        g[6] =  ct * cA; g[7] =  ct * sA;   // g11
    }
}

// ---------- main kernel ----------
// (256, 2): grid is capped at 2048 waves = 2/SIMD anyway -> allow 256 VGPRs
__global__ __launch_bounds__(64 * WPB, 2) void qembed(
    const float* __restrict__ z,     // (B, CDIM)
    const float* __restrict__ Win,   // (CDIM, NQ)
    const float* __restrict__ bin,   // (NQ)
    const float* __restrict__ gates, // (NL*NQ, 8) precomputed
    const float* __restrict__ Wout,  // (NQ, CDIM)
    const float* __restrict__ bout,  // (CDIM)
    float* __restrict__ out)         // (B, CDIM)
{
    const int wave = threadIdx.x >> 6;
    const int lane = threadIdx.x & 63;
    const int samp = blockIdx.x * WPB + wave;

    // ---- angles = z[samp] @ Win + bin ----
    float ang[NQ];
    {
        float acc[NQ];
#pragma unroll
        for (int q = 0; q < NQ; ++q) acc[q] = 0.f;
        const float* zrow = z + (size_t)samp * CDIM;
#pragma unroll
        for (int j = 0; j < CDIM / 64; ++j) {
            const int k = lane + j * 64;
            const float zv = zrow[k];
            const f2* wr = (const f2*)(Win + k * NQ);   // 8B-aligned (k*10 even)
#pragma unroll
            for (int h = 0; h < NQ / 2; ++h) {
                const f2 w = wr[h];
                acc[2 * h]     += zv * w.x;
                acc[2 * h + 1] += zv * w.y;
            }
        }
#pragma unroll
        for (int q = 0; q < NQ; ++q) ang[q] = wave_sum(acc[q]) + bin[q];
    }

    // ---- layer 0 on |0..0>: product state built directly ----
    // fused F_q = Rot(l0,q) * RX(ang_q); only its first column (f0,f1) matters
    f2 f0[NQ], f1[NQ];
    {
        const float4* g4 = (const float4*)gates;       // uniform -> s_load
#pragma unroll
        for (int q = 0; q < NQ; ++q) {
            const float4 p0 = g4[q * 2];
            const float4 p1 = g4[q * 2 + 1];
            float s, c;
            __sincosf(0.5f * ang[q], &s, &c);
            f2 a, b;
            a.x = p0.x * c + s * p0.w;  a.y = p0.y * c - s * p0.z;
            b.x = p1.x * c + s * p1.w;  b.y = p1.y * c - s * p1.z;
            f0[q] = a; f1[q] = b;
        }
    }
    // lane-bit factors: bit b (0..5) <-> wire 9-b
    f2 s0 = ((lane >> 0) & 1) ? f1[9] : f0[9];
    f2 s1 = ((lane >> 1) & 1) ? f1[8] : f0[8];
    f2 s2 = ((lane >> 2) & 1) ? f1[7] : f0[7];
    f2 s3 = ((lane >> 3) & 1) ? f1[6] : f0[6];
    f2 s4 = ((lane >> 4) & 1) ? f1[5] : f0[5];
    f2 s5 = ((lane >> 5) & 1) ? f1[4] : f0[4];
    const f2 L = cmul(cmul(cmul(s0, s1), cmul(s2, s3)), cmul(s4, s5));

    f2 LT[4], U2[4];
#pragma unroll
    for (int j = 0; j < 4; ++j) {
        // reg bits 0,1 <-> index bits 6,7 <-> wires 3,2
        const f2 t = cmul((j & 1) ? f1[3] : f0[3], (j & 2) ? f1[2] : f0[2]);
        LT[j] = cmul(L, t);
        // reg bits 2,3 <-> index bits 8,9 <-> wires 1,0
        U2[j] = cmul((j & 1) ? f1[1] : f0[1], (j & 2) ? f1[0] : f0[0]);
    }
    f2 v[NREG];
#pragma unroll
    for (int r = 0; r < NREG; ++r) v[r] = cmul(LT[r & 3], U2[r >> 2]);

    // ---- remaining circuit (ring 2 absorbed into measurement) ----
    cnot_ring<0>(v, lane);
    rot_layer<1>(v, lane, gates);  cnot_ring<1>(v, lane);
    rot_layer<2>(v, lane, gates);

    // ---- expectation values with ring-2 parity masks ----
    float pr[NREG];
#pragma unroll
    for (int r = 0; r < NREG; ++r) pr[r] = v[r].x * v[r].x + v[r].y * v[r].y;

    float ev[NQ];
    measure_all(pr, lane, ev);

    // ---- out[samp] = ev @ Wout + bout ----
#pragma unroll
    for (int j = 0; j < CDIM / 64; ++j) {
        const int d = lane + j * 64;
        float o = bout[d];
#pragma unroll
        for (int q = 0; q < NQ; ++q) o += ev[q] * Wout[q * CDIM + d];
        out[(size_t)samp * CDIM + d] = o;
    }
}

extern "C" void kernel_launch(void* const* d_in, const int* in_sizes, int n_in,
                              void* d_out, int out_size, void* d_ws, size_t ws_size,
                              hipStream_t stream) {
    const float* z    = (const float*)d_in[0];
    const float* Win  = (const float*)d_in[1];
    const float* bin  = (const float*)d_in[2];
    const float* wts  = (const float*)d_in[3];
    const float* Wout = (const float*)d_in[4];
    const float* bout = (const float*)d_in[5];
    float* outp       = (float*)d_out;
    float* gates      = (float*)d_ws;       // 30 gates * 8 floats = 960 B

    prep_gates<<<1, 64, 0, stream>>>(wts, gates);

    const int batch  = in_sizes[0] / CDIM;   // 2048
    const int blocks = batch / WPB;          // 512
    qembed<<<blocks, 64 * WPB, 0, stream>>>(z, Win, bin, gates, Wout, bout, outp);
}

// Round 9
// 31.418 us; speedup vs baseline: 1.1441x; 1.1036x over previous
//
#include <hip/hip_runtime.h>

typedef float f2 __attribute__((ext_vector_type(2)));   // complex (re, im)

constexpr int NQ   = 10;
constexpr int CDIM = 768;
constexpr int NL   = 3;
constexpr int NREG = 16;   // index bits 6..9 in the register index
constexpr int WPB  = 4;    // waves (= samples) per block

// ---------- cross-lane primitives (all VALU, no LDS pipe) ----------

template<int CTRL>
__device__ __forceinline__ float dppmov(float x) {
    return __int_as_float(__builtin_amdgcn_update_dpp(
        __float_as_int(x), __float_as_int(x), CTRL, 0xF, 0xF, true));
}

// y[l] = x[l ^ MASK] for MASK in {1,2,4,8}
template<int MASK>
__device__ __forceinline__ float lxor(float x, int lane) {
    static_assert(MASK == 1 || MASK == 2 || MASK == 4 || MASK == 8, "");
    if constexpr (MASK == 1)      return dppmov<0xB1>(x);   // quad_perm [1,0,3,2]
    else if constexpr (MASK == 2) return dppmov<0x4E>(x);   // quad_perm [2,3,0,1]
    else if constexpr (MASK == 4) {
        const float a = dppmov<0x104>(x);   // row_shl:4 -> src[i+4] (bit2=0 lanes)
        const float b = dppmov<0x114>(x);   // row_shr:4 -> src[i-4] (bit2=1 lanes)
        return ((lane >> 2) & 1) ? b : a;
    }
    else                          return dppmov<0x128>(x);  // row_ror:8 == xor8
}

// B in {4,5}: lo = x[l & ~(1<<B)], hi = x[l | (1<<B)]  (one swap instr)
template<int B>
__device__ __forceinline__ void swap2(float x, float& lo, float& hi) {
    const unsigned xu = __float_as_uint(x);
#if __has_builtin(__builtin_amdgcn_permlane16_swap) && __has_builtin(__builtin_amdgcn_permlane32_swap)
    if constexpr (B == 4) {
        auto r = __builtin_amdgcn_permlane16_swap(xu, xu, false, false);
        lo = __uint_as_float(r[0]); hi = __uint_as_float(r[1]);
    } else {
        auto r = __builtin_amdgcn_permlane32_swap(xu, xu, false, false);
        lo = __uint_as_float(r[0]); hi = __uint_as_float(r[1]);
    }
#else
    float d, s;
    if constexpr (B == 4)
        asm("v_mov_b32 %0, %2\n\tv_mov_b32 %1, %2\n\ts_nop 1\n\t"
            "v_permlane16_swap_b32 %0, %1"
            : "=&v"(d), "=&v"(s) : "v"(x));
    else
        asm("v_mov_b32 %0, %2\n\tv_mov_b32 %1, %2\n\ts_nop 1\n\t"
            "v_permlane32_swap_b32 %0, %1"
            : "=&v"(d), "=&v"(s) : "v"(x));
    lo = d; hi = s;
#endif
}

__device__ __forceinline__ float wave_sum(float v) {
    v += dppmov<0xB1>(v);    // xor1
    v += dppmov<0x4E>(v);    // xor2
    v += dppmov<0x141>(v);   // row_half_mirror = xor7 (bits 0-1 uniform)
    v += dppmov<0x140>(v);   // row_mirror = xor15 (bits 0-2 uniform)
    float lo, hi;
    swap2<4>(v, lo, hi); v = lo + hi;
    swap2<5>(v, lo, hi); v = lo + hi;
    return v;
}

// ---------- complex helpers (packed-math friendly) ----------

__device__ __forceinline__ f2 swapneg(f2 b) { f2 r; r.x = -b.y; r.y = b.x; return r; }
__device__ __forceinline__ f2 cmul(f2 a, f2 b) { return b * a.x + swapneg(b) * a.y; }
__device__ __forceinline__ f2 cfma(f2 a, f2 b, f2 acc) { return acc + b * a.x + swapneg(b) * a.y; }

// ---------- 1-qubit gate on index-bit B (wire w -> B = 9 - w) ----------

template<int B>
__device__ __forceinline__ void gate_bit(f2 (&v)[NREG], int lane,
                                         f2 g00, f2 g01, f2 g10, f2 g11) {
    if constexpr (B >= 6) {                       // register bit: pure in-reg
        constexpr int rb = B - 6;
#pragma unroll
        for (int p = 0; p < NREG / 2; ++p) {
            const int r0 = ((p >> rb) << (rb + 1)) | (p & ((1 << rb) - 1));
            const int r1 = r0 | (1 << rb);
            const f2 a0 = v[r0], a1 = v[r1];
            v[r0] = cfma(g01, a1, cmul(g00, a0));
            v[r1] = cfma(g11, a1, cmul(g10, a0));
        }
    } else if constexpr (B >= 4) {                // lane bit via permlane swap
        const bool hb = (lane >> B) & 1;
        const f2 A  = hb ? g10 : g00;             // coeff on lo value
        const f2 Bc = hb ? g11 : g01;             // coeff on hi value
#pragma unroll
        for (int r = 0; r < NREG; ++r) {
            float lx, hx, ly, hy;
            swap2<B>(v[r].x, lx, hx);
            swap2<B>(v[r].y, ly, hy);
            f2 lo; lo.x = lx; lo.y = ly;
            f2 hi; hi.x = hx; hi.y = hy;
            v[r] = cfma(Bc, hi, cmul(A, lo));
        }
    } else {                                      // lane bit via DPP
        const bool hb = (lane >> B) & 1;
        const f2 cO = hb ? g11 : g00;
        const f2 cP = hb ? g10 : g01;
#pragma unroll
        for (int r = 0; r < NREG; ++r) {
            f2 p;
            p.x = lxor<(1 << B)>(v[r].x, lane);
            p.y = lxor<(1 << B)>(v[r].y, lane);
            v[r] = cfma(cP, p, cmul(cO, v[r]));
        }
    }
}

// partner value x[l ^ (1<<BT)] for lane-resident target bit
template<int BT>
__device__ __forceinline__ float partner(float x, int lane) {
    if constexpr (BT >= 4) {
        float lo, hi; swap2<BT>(x, lo, hi);
        return ((lane >> BT) & 1) ? lo : hi;
    } else return lxor<(1 << BT)>(x, lane);
}

// ---------- CNOT ----------

template<int BC, int BT>
__device__ __forceinline__ void cnot(f2 (&v)[NREG], int lane) {
    if constexpr (BC >= 6 && BT >= 6) {           // both reg: free rename
        constexpr int rc = BC - 6, rt = BT - 6;
#pragma unroll
        for (int r = 0; r < NREG; ++r)
            if (((r >> rc) & 1) && !((r >> rt) & 1)) {
                const int r1 = r | (1 << rt);
                const f2 t = v[r]; v[r] = v[r1]; v[r1] = t;
            }
    } else if constexpr (BC >= 6) {               // reg control, lane target
        constexpr int rc = BC - 6;
#pragma unroll
        for (int r = 0; r < NREG; ++r)
            if ((r >> rc) & 1) {
                f2 n;
                n.x = partner<BT>(v[r].x, lane);
                n.y = partner<BT>(v[r].y, lane);
                v[r] = n;
            }
    } else if constexpr (BT >= 6) {               // lane control, reg target
        constexpr int rt = BT - 6;
        const bool c = (lane >> BC) & 1;
#pragma unroll
        for (int p = 0; p < NREG / 2; ++p) {
            const int r0 = ((p >> rt) << (rt + 1)) | (p & ((1 << rt) - 1));
            const int r1 = r0 | (1 << rt);
            const f2 a = v[r0], b = v[r1];
            v[r0] = c ? b : a;
            v[r1] = c ? a : b;
        }
    } else {                                      // both lane
        const bool c = (lane >> BC) & 1;
#pragma unroll
        for (int r = 0; r < NREG; ++r) {
            f2 n;
            n.x = c ? partner<BT>(v[r].x, lane) : v[r].x;
            n.y = c ? partner<BT>(v[r].y, lane) : v[r].y;
            v[r] = n;
        }
    }
}

// ---------- layer drivers (gates computed on the fly, wave-uniform VGPRs) ----------

template<int L, int Q = 0>
__device__ __forceinline__ void rot_layer_otf(f2 (&v)[NREG], int lane,
                                              const float* __restrict__ wts) {
    if constexpr (Q < NQ) {
        const float phi = wts[(L * NQ + Q) * 3 + 0];   // uniform -> s_load
        const float th  = wts[(L * NQ + Q) * 3 + 1];
        const float om  = wts[(L * NQ + Q) * 3 + 2];
        float st, ct, sA, cA, sB, cB;
        __sincosf(0.5f * th, &st, &ct);
        __sincosf(0.5f * (phi + om), &sA, &cA);
        __sincosf(0.5f * (phi - om), &sB, &cB);
        f2 g00 = { ct * cA, -ct * sA};
        f2 g01 = {-st * cB, -st * sB};
        f2 g10 = { st * cB, -st * sB};
        f2 g11 = { ct * cA,  ct * sA};
        gate_bit<9 - Q>(v, lane, g00, g01, g10, g11);
        rot_layer_otf<L, Q + 1>(v, lane, wts);
    }
}

template<int L, int I = 0>
__device__ __forceinline__ void cnot_ring(f2 (&v)[NREG], int lane) {
    if constexpr (I < NQ) {
        constexpr int R = (L % (NQ - 1)) + 1;
        cnot<9 - I, 9 - ((I + R) % NQ)>(v, lane);
        cnot_ring<L, I + 1>(v, lane);
    }
}

// ---------- ring-2 absorbed measurement ----------
// Final CNOT ring (r=3) is a classical permutation; measuring Z_w after it
// equals measuring parity(x & M_w) before it, with M_t ^= M_c accumulated in
// gate order (current values). Computed at compile time.
constexpr unsigned ring2_mask(int w) {
    unsigned M[NQ] = {};
    for (int i = 0; i < NQ; ++i) M[i] = 1u << (9 - i);
    for (int i = 0; i < NQ; ++i) M[(i + 3) % NQ] ^= M[i];
    return M[w];
}

template<unsigned MR>
__device__ __forceinline__ float regsum16(const float (&pr)[NREG]) {
    float s = 0.f;
#pragma unroll
    for (int r = 0; r < NREG; ++r)
        s = (__builtin_popcount((unsigned)r & MR) & 1) ? s - pr[r] : s + pr[r];
    return s;
}

template<int W = 0>
__device__ __forceinline__ void measure_all(const float (&pr)[NREG], int lane,
                                            float (&ev)[NQ]) {
    if constexpr (W < NQ) {
        constexpr unsigned m  = ring2_mask(W);
        constexpr unsigned mr = (m >> 6) & 0xFu;   // register-bit part
        constexpr unsigned ml = m & 63u;           // lane-bit part
        float s = regsum16<mr>(pr);
        if constexpr (ml != 0) {
            const unsigned flip = (unsigned)((__popc(lane & (int)ml) & 1)) << 31;
            s = __uint_as_float(__float_as_uint(s) ^ flip);
        }
        ev[W] = wave_sum(s);
        measure_all<W + 1>(pr, lane, ev);
    }
}

// ---------- main kernel (single launch, no prep) ----------
// (256, 2): grid is capped at 2048 waves = 2/SIMD anyway -> allow 256 VGPRs
__global__ __launch_bounds__(64 * WPB, 2) void qembed(
    const float* __restrict__ z,     // (B, CDIM)
    const float* __restrict__ Win,   // (CDIM, NQ)
    const float* __restrict__ bin,   // (NQ)
    const float* __restrict__ wts,   // (NL, NQ, 3)
    const float* __restrict__ Wout,  // (NQ, CDIM)
    const float* __restrict__ bout,  // (CDIM)
    float* __restrict__ out)         // (B, CDIM)
{
    const int wave = threadIdx.x >> 6;
    const int lane = threadIdx.x & 63;
    const int samp = blockIdx.x * WPB + wave;

    // ---- angles = z[samp] @ Win + bin (z batched first) ----
    float ang[NQ];
    {
        const float* zrow = z + (size_t)samp * CDIM;
        float zr[CDIM / 64];
#pragma unroll
        for (int j = 0; j < CDIM / 64; ++j) zr[j] = zrow[lane + j * 64];

        float acc[NQ];
#pragma unroll
        for (int q = 0; q < NQ; ++q) acc[q] = 0.f;
#pragma unroll
        for (int j = 0; j < CDIM / 64; ++j) {
            const int k = lane + j * 64;
            const f2* wr = (const f2*)(Win + k * NQ);   // 8B-aligned (k*10 even)
#pragma unroll
            for (int h = 0; h < NQ / 2; ++h) {
                const f2 w = wr[h];
                acc[2 * h]     += zr[j] * w.x;
                acc[2 * h + 1] += zr[j] * w.y;
            }
        }
#pragma unroll
        for (int q = 0; q < NQ; ++q) ang[q] = wave_sum(acc[q]) + bin[q];
    }

    // ---- layer 0 on |0..0>: product state built directly ----
    // fused F_q = Rot(l0,q) * RX(ang_q); only its first column (f0,f1) matters
    f2 f0[NQ], f1[NQ];
#pragma unroll
    for (int q = 0; q < NQ; ++q) {
        const float phi = wts[q * 3 + 0];   // uniform -> s_load
        const float th  = wts[q * 3 + 1];
        const float om  = wts[q * 3 + 2];
        float st, ct, sA, cA, sB, cB, s, c;
        __sincosf(0.5f * th, &st, &ct);
        __sincosf(0.5f * (phi + om), &sA, &cA);
        __sincosf(0.5f * (phi - om), &sB, &cB);
        __sincosf(0.5f * ang[q], &s, &c);
        const float g00x =  ct * cA, g00y = -ct * sA;
        const float g01x = -st * cB, g01y = -st * sB;
        const float g10x =  st * cB, g10y = -st * sB;
        const float g11x =  ct * cA, g11y =  ct * sA;
        f2 a, b;
        a.x = g00x * c + s * g01y;  a.y = g00y * c - s * g01x;
        b.x = g10x * c + s * g11y;  b.y = g10y * c - s * g11x;
        f0[q] = a; f1[q] = b;
    }
    // lane-bit factors: bit b (0..5) <-> wire 9-b
    f2 s0 = ((lane >> 0) & 1) ? f1[9] : f0[9];
    f2 s1 = ((lane >> 1) & 1) ? f1[8] : f0[8];
    f2 s2 = ((lane >> 2) & 1) ? f1[7] : f0[7];
    f2 s3 = ((lane >> 3) & 1) ? f1[6] : f0[6];
    f2 s4 = ((lane >> 4) & 1) ? f1[5] : f0[5];
    f2 s5 = ((lane >> 5) & 1) ? f1[4] : f0[4];
    const f2 L = cmul(cmul(cmul(s0, s1), cmul(s2, s3)), cmul(s4, s5));

    f2 LT[4], U2[4];
#pragma unroll
    for (int j = 0; j < 4; ++j) {
        // reg bits 0,1 <-> index bits 6,7 <-> wires 3,2
        const f2 t = cmul((j & 1) ? f1[3] : f0[3], (j & 2) ? f1[2] : f0[2]);
        LT[j] = cmul(L, t);
        // reg bits 2,3 <-> index bits 8,9 <-> wires 1,0
        U2[j] = cmul((j & 1) ? f1[1] : f0[1], (j & 2) ? f1[0] : f0[0]);
    }
    f2 v[NREG];
#pragma unroll
    for (int r = 0; r < NREG; ++r) v[r] = cmul(LT[r & 3], U2[r >> 2]);

    // ---- remaining circuit (ring 2 absorbed into measurement) ----
    cnot_ring<0>(v, lane);
    rot_layer_otf<1>(v, lane, wts);  cnot_ring<1>(v, lane);
    rot_layer_otf<2>(v, lane, wts);

    // ---- expectation values with ring-2 parity masks ----
    float pr[NREG];
#pragma unroll
    for (int r = 0; r < NREG; ++r) pr[r] = v[r].x * v[r].x + v[r].y * v[r].y;

    float ev[NQ];
    measure_all(pr, lane, ev);

    // ---- out[samp] = ev @ Wout + bout (load-all-then-FMA halves) ----
#pragma unroll
    for (int half = 0; half < 2; ++half) {
        float wr[6][NQ];
        float bo[6];
#pragma unroll
        for (int j = 0; j < 6; ++j) {
            const int d = lane + (half * 6 + j) * 64;
            bo[j] = bout[d];
#pragma unroll
            for (int q = 0; q < NQ; ++q) wr[j][q] = Wout[q * CDIM + d];
        }
#pragma unroll
        for (int j = 0; j < 6; ++j) {
            const int d = lane + (half * 6 + j) * 64;
            float o = bo[j];
#pragma unroll
            for (int q = 0; q < NQ; ++q) o += ev[q] * wr[j][q];
            out[(size_t)samp * CDIM + d] = o;
        }
    }
}

extern "C" void kernel_launch(void* const* d_in, const int* in_sizes, int n_in,
                              void* d_out, int out_size, void* d_ws, size_t ws_size,
                              hipStream_t stream) {
    const float* z    = (const float*)d_in[0];
    const float* Win  = (const float*)d_in[1];
    const float* bin  = (const float*)d_in[2];
    const float* wts  = (const float*)d_in[3];
    const float* Wout = (const float*)d_in[4];
    const float* bout = (const float*)d_in[5];
    float* outp       = (float*)d_out;

    const int batch  = in_sizes[0] / CDIM;   // 2048
    const int blocks = batch / WPB;          // 512
    qembed<<<blocks, 64 * WPB, 0, stream>>>(z, Win, bin, wts, Wout, bout, outp);
}